// Round 1
// baseline (237.108 us; speedup 1.0000x reference)
//
#include <hip/hip_runtime.h>

// loss = W_I * 0.5*mean(m*a^2)  +  W_G * (-mean(m*g*y))  +  W_S * mean(psi*vol)
// Folded into per-term scales applied per element, accumulated into one double.

#define GRAVITY_F 9.81f

__device__ __forceinline__ float blockReduceSum(float val) {
    // wave (64-lane) butterfly via shfl_down
    #pragma unroll
    for (int off = 32; off > 0; off >>= 1)
        val += __shfl_down(val, off, 64);
    __shared__ float smem[16];
    const int lane = threadIdx.x & 63;
    const int wave = threadIdx.x >> 6;
    if (lane == 0) smem[wave] = val;
    __syncthreads();
    const int nwaves = (blockDim.x + 63) >> 6;
    val = 0.0f;
    if (wave == 0) {
        if (lane < nwaves) val = smem[lane];
        #pragma unroll
        for (int off = 8; off > 0; off >>= 1)
            val += __shfl_down(val, off, 64);
    }
    return val;  // valid on thread 0 only
}

__global__ void init_acc_kernel(double* acc) {
    if (threadIdx.x == 0 && blockIdx.x == 0) acc[0] = 0.0;
}

__global__ void vert_kernel(const float* __restrict__ pn,
                            const float* __restrict__ pc,
                            const float* __restrict__ pp,
                            const float* __restrict__ mass,
                            double* __restrict__ acc,
                            int V, float sI, float sG) {
    float local = 0.0f;
    for (int v = blockIdx.x * blockDim.x + threadIdx.x; v < V;
         v += gridDim.x * blockDim.x) {
        const float m  = mass[v];
        const float p0 = pc[3 * v + 0];
        const float y  = pc[3 * v + 1];
        const float p2 = pc[3 * v + 2];
        const float a0 = pn[3 * v + 0] + pp[3 * v + 0] - 2.0f * p0;
        const float a1 = pn[3 * v + 1] + pp[3 * v + 1] - 2.0f * y;
        const float a2 = pn[3 * v + 2] + pp[3 * v + 2] - 2.0f * p2;
        local += sI * (m * (a0 * a0 + a1 * a1 + a2 * a2)) + sG * (m * y);
    }
    const float tot = blockReduceSum(local);
    if (threadIdx.x == 0) atomicAdd(acc, (double)tot);
}

__global__ void elem_kernel(const float* __restrict__ pn,
                            const int*   __restrict__ elems,
                            const float* __restrict__ vols,
                            const float* __restrict__ rinv,
                            const float* __restrict__ lam_p,
                            const float* __restrict__ mu_p,
                            double* __restrict__ acc,
                            int E, float sS) {
    const float lam = lam_p[0];
    const float mu  = mu_p[0];
    float local = 0.0f;
    for (int e = blockIdx.x * blockDim.x + threadIdx.x; e < E;
         e += gridDim.x * blockDim.x) {
        const int4 idx = ((const int4*)elems)[e];
        const float* v0 = pn + 3 * (size_t)idx.x;
        const float* v1 = pn + 3 * (size_t)idx.y;
        const float* v2 = pn + 3 * (size_t)idx.z;
        const float* v3 = pn + 3 * (size_t)idx.w;

        // Ds[i][j]: column j = v_{j+1} - v0, row i = coordinate
        float d[3][3];
        #pragma unroll
        for (int i = 0; i < 3; ++i) {
            const float b = v0[i];
            d[i][0] = v1[i] - b;
            d[i][1] = v2[i] - b;
            d[i][2] = v3[i] - b;
        }

        const float* R = rinv + 9 * (size_t)e;  // row-major R[j][k]
        float F[3][3];
        #pragma unroll
        for (int i = 0; i < 3; ++i) {
            #pragma unroll
            for (int k = 0; k < 3; ++k) {
                F[i][k] = d[i][0] * R[0 * 3 + k]
                        + d[i][1] * R[1 * 3 + k]
                        + d[i][2] * R[2 * 3 + k];
            }
        }

        const float det = F[0][0] * (F[1][1] * F[2][2] - F[1][2] * F[2][1])
                        - F[0][1] * (F[1][0] * F[2][2] - F[1][2] * F[2][0])
                        + F[0][2] * (F[1][0] * F[2][1] - F[1][1] * F[2][0]);
        const float ld = logf(fmaxf(det, 1e-8f));
        float tr = 0.0f;
        #pragma unroll
        for (int i = 0; i < 3; ++i)
            #pragma unroll
            for (int k = 0; k < 3; ++k)
                tr += F[i][k] * F[i][k];

        const float psi = 0.5f * lam * ld * ld - mu * ld + 0.5f * mu * (tr - 3.0f);
        local += sS * (psi * vols[e]);
    }
    const float tot = blockReduceSum(local);
    if (threadIdx.x == 0) atomicAdd(acc, (double)tot);
}

__global__ void finalize_kernel(const double* __restrict__ acc,
                                float* __restrict__ out) {
    if (threadIdx.x == 0 && blockIdx.x == 0) out[0] = (float)acc[0];
}

extern "C" void kernel_launch(void* const* d_in, const int* in_sizes, int n_in,
                              void* d_out, int out_size, void* d_ws, size_t ws_size,
                              hipStream_t stream) {
    const float* pos_next = (const float*)d_in[0];
    const float* pos_curr = (const float*)d_in[1];
    const float* pos_prev = (const float*)d_in[2];
    const float* mass     = (const float*)d_in[3];
    const int*   elements = (const int*)d_in[4];
    const float* rest_vol = (const float*)d_in[5];
    const float* rest_inv = (const float*)d_in[6];
    const float* lam_p    = (const float*)d_in[7];
    const float* mu_p     = (const float*)d_in[8];
    float* out = (float*)d_out;

    const int V = in_sizes[3];  // mass has V elements
    const int E = in_sizes[5];  // rest_volumes has E elements

    double* acc = (double*)d_ws;

    const float sI = 0.5f / (3.0f * (float)V);              // W_INERTIA * 0.5 / (3V)
    const float sG = -0.01f * GRAVITY_F / (float)V;         // W_GRAVITY * (-g) / V
    const float sS = 1.0f / (float)E;                       // W_STRAIN / E

    init_acc_kernel<<<1, 1, 0, stream>>>(acc);
    {
        const int block = 256;
        int grid = (V + block - 1) / block;
        if (grid > 1024) grid = 1024;
        vert_kernel<<<grid, block, 0, stream>>>(pos_next, pos_curr, pos_prev,
                                                mass, acc, V, sI, sG);
    }
    {
        const int block = 256;
        int grid = (E + block - 1) / block;
        if (grid > 2048) grid = 2048;
        elem_kernel<<<grid, block, 0, stream>>>(pos_next, elements, rest_vol,
                                                rest_inv, lam_p, mu_p, acc, E, sS);
    }
    finalize_kernel<<<1, 1, 0, stream>>>(acc, out);
}

// Round 2
// 229.941 us; speedup vs baseline: 1.0312x; 1.0312x over previous
//
#include <hip/hip_runtime.h>

#define GRAVITY_F 9.81f

__device__ __forceinline__ float blockReduceSum(float val) {
    #pragma unroll
    for (int off = 32; off > 0; off >>= 1)
        val += __shfl_down(val, off, 64);
    __shared__ float smem[16];
    const int lane = threadIdx.x & 63;
    const int wave = threadIdx.x >> 6;
    if (lane == 0) smem[wave] = val;
    __syncthreads();
    const int nwaves = (blockDim.x + 63) >> 6;
    val = 0.0f;
    if (wave == 0) {
        if (lane < nwaves) val = smem[lane];
        #pragma unroll
        for (int off = 8; off > 0; off >>= 1)
            val += __shfl_down(val, off, 64);
    }
    return val;  // valid on thread 0 only
}

// One item per thread over [0, V+E): first V items are vertex terms,
// the rest are element (strain) terms. Each block writes exactly one
// float partial (no init needed — every slot is overwritten).
__global__ void fused_kernel(const float* __restrict__ pn,
                             const float* __restrict__ pc,
                             const float* __restrict__ pp,
                             const float* __restrict__ mass,
                             const int*   __restrict__ elems,
                             const float* __restrict__ vols,
                             const float* __restrict__ rinv,
                             const float* __restrict__ lam_p,
                             const float* __restrict__ mu_p,
                             float* __restrict__ partials,
                             double* __restrict__ acc,
                             int V, int E,
                             float sI, float sG, float sS) {
    const int i = blockIdx.x * blockDim.x + threadIdx.x;
    float local = 0.0f;

    if (i < V) {
        const int v = i;
        const float m  = mass[v];
        const float p0 = pc[3 * v + 0];
        const float y  = pc[3 * v + 1];
        const float p2 = pc[3 * v + 2];
        const float a0 = pn[3 * v + 0] + pp[3 * v + 0] - 2.0f * p0;
        const float a1 = pn[3 * v + 1] + pp[3 * v + 1] - 2.0f * y;
        const float a2 = pn[3 * v + 2] + pp[3 * v + 2] - 2.0f * p2;
        local = sI * (m * (a0 * a0 + a1 * a1 + a2 * a2)) + sG * (m * y);
    } else if (i < V + E) {
        const int e = i - V;
        const float lam = lam_p[0];
        const float mu  = mu_p[0];
        const int4 idx = ((const int4*)elems)[e];
        const float* v0 = pn + 3 * (size_t)idx.x;
        const float* v1 = pn + 3 * (size_t)idx.y;
        const float* v2 = pn + 3 * (size_t)idx.z;
        const float* v3 = pn + 3 * (size_t)idx.w;

        float d[3][3];
        #pragma unroll
        for (int r = 0; r < 3; ++r) {
            const float b = v0[r];
            d[r][0] = v1[r] - b;
            d[r][1] = v2[r] - b;
            d[r][2] = v3[r] - b;
        }

        const float* R = rinv + 9 * (size_t)e;  // row-major R[j][k]
        float F[3][3];
        #pragma unroll
        for (int r = 0; r < 3; ++r) {
            #pragma unroll
            for (int k = 0; k < 3; ++k) {
                F[r][k] = d[r][0] * R[0 * 3 + k]
                        + d[r][1] * R[1 * 3 + k]
                        + d[r][2] * R[2 * 3 + k];
            }
        }

        const float det = F[0][0] * (F[1][1] * F[2][2] - F[1][2] * F[2][1])
                        - F[0][1] * (F[1][0] * F[2][2] - F[1][2] * F[2][0])
                        + F[0][2] * (F[1][0] * F[2][1] - F[1][1] * F[2][0]);
        const float ld = logf(fmaxf(det, 1e-8f));
        float tr = 0.0f;
        #pragma unroll
        for (int r = 0; r < 3; ++r)
            #pragma unroll
            for (int k = 0; k < 3; ++k)
                tr += F[r][k] * F[r][k];

        const float psi = 0.5f * lam * ld * ld - mu * ld + 0.5f * mu * (tr - 3.0f);
        local = sS * (psi * vols[e]);
    }

    const float tot = blockReduceSum(local);
    if (threadIdx.x == 0) {
        if (partials) partials[blockIdx.x] = tot;
        else atomicAdd(acc, (double)tot);
    }
}

__global__ void reduce_kernel(const float* __restrict__ partials, int n,
                              float* __restrict__ out) {
    double s = 0.0;
    for (int i = threadIdx.x; i < n; i += blockDim.x)
        s += (double)partials[i];
    __shared__ double sm[256];
    sm[threadIdx.x] = s;
    __syncthreads();
    #pragma unroll
    for (int off = 128; off > 0; off >>= 1) {
        if (threadIdx.x < off) sm[threadIdx.x] += sm[threadIdx.x + off];
        __syncthreads();
    }
    if (threadIdx.x == 0) out[0] = (float)sm[0];
}

// Fallback path kernels (only used if d_ws is too small for block partials)
__global__ void init_acc_kernel(double* acc) {
    if (threadIdx.x == 0 && blockIdx.x == 0) acc[0] = 0.0;
}
__global__ void finalize_kernel(const double* __restrict__ acc,
                                float* __restrict__ out) {
    if (threadIdx.x == 0 && blockIdx.x == 0) out[0] = (float)acc[0];
}

extern "C" void kernel_launch(void* const* d_in, const int* in_sizes, int n_in,
                              void* d_out, int out_size, void* d_ws, size_t ws_size,
                              hipStream_t stream) {
    const float* pos_next = (const float*)d_in[0];
    const float* pos_curr = (const float*)d_in[1];
    const float* pos_prev = (const float*)d_in[2];
    const float* mass     = (const float*)d_in[3];
    const int*   elements = (const int*)d_in[4];
    const float* rest_vol = (const float*)d_in[5];
    const float* rest_inv = (const float*)d_in[6];
    const float* lam_p    = (const float*)d_in[7];
    const float* mu_p     = (const float*)d_in[8];
    float* out = (float*)d_out;

    const int V = in_sizes[3];  // mass has V elements
    const int E = in_sizes[5];  // rest_volumes has E elements

    const float sI = 0.5f / (3.0f * (float)V);       // W_INERTIA * 0.5 / (3V)
    const float sG = -0.01f * GRAVITY_F / (float)V;  // W_GRAVITY * (-g) / V
    const float sS = 1.0f / (float)E;                // W_STRAIN / E

    const int block = 256;
    const int nitems = V + E;
    const int grid = (nitems + block - 1) / block;

    const bool use_partials = ws_size >= (size_t)grid * sizeof(float) + 64;

    if (use_partials) {
        float* partials = (float*)d_ws;
        fused_kernel<<<grid, block, 0, stream>>>(pos_next, pos_curr, pos_prev,
                                                 mass, elements, rest_vol,
                                                 rest_inv, lam_p, mu_p,
                                                 partials, nullptr,
                                                 V, E, sI, sG, sS);
        reduce_kernel<<<1, 256, 0, stream>>>(partials, grid, out);
    } else {
        double* acc = (double*)d_ws;
        init_acc_kernel<<<1, 1, 0, stream>>>(acc);
        fused_kernel<<<grid, block, 0, stream>>>(pos_next, pos_curr, pos_prev,
                                                 mass, elements, rest_vol,
                                                 rest_inv, lam_p, mu_p,
                                                 nullptr, acc,
                                                 V, E, sI, sG, sS);
        finalize_kernel<<<1, 1, 0, stream>>>(acc, out);
    }
}

// Round 4
// 226.656 us; speedup vs baseline: 1.0461x; 1.0145x over previous
//
#include <hip/hip_runtime.h>

#define GRAVITY_F 9.81f

typedef int v4i __attribute__((ext_vector_type(4)));

__device__ __forceinline__ float blockReduceSum(float val) {
    #pragma unroll
    for (int off = 32; off > 0; off >>= 1)
        val += __shfl_down(val, off, 64);
    __shared__ float smem[16];
    const int lane = threadIdx.x & 63;
    const int wave = threadIdx.x >> 6;
    if (lane == 0) smem[wave] = val;
    __syncthreads();
    const int nwaves = (blockDim.x + 63) >> 6;
    val = 0.0f;
    if (wave == 0) {
        if (lane < nwaves) val = smem[lane];
        #pragma unroll
        for (int off = 8; off > 0; off >>= 1)
            val += __shfl_down(val, off, 64);
    }
    return val;  // valid on thread 0 only
}

__device__ __forceinline__ float elem_term(const float* __restrict__ pn,
                                           const v4i idx,
                                           const float vol,
                                           const float* __restrict__ R,
                                           float lam, float mu, float sS) {
    // gathers (cached — pos_next is the reused array, keep it in L2)
    float x0[3], x1[3], x2[3], x3[3];
    const float* v0 = pn + 3 * (size_t)idx.x;
    const float* v1 = pn + 3 * (size_t)idx.y;
    const float* v2 = pn + 3 * (size_t)idx.z;
    const float* v3 = pn + 3 * (size_t)idx.w;
    #pragma unroll
    for (int r = 0; r < 3; ++r) { x0[r] = v0[r]; x1[r] = v1[r]; x2[r] = v2[r]; x3[r] = v3[r]; }

    // rest_inv: streamed once — nontemporal
    float Rv[9];
    #pragma unroll
    for (int k = 0; k < 9; ++k) Rv[k] = __builtin_nontemporal_load(R + k);

    float d[3][3];
    #pragma unroll
    for (int r = 0; r < 3; ++r) {
        d[r][0] = x1[r] - x0[r];
        d[r][1] = x2[r] - x0[r];
        d[r][2] = x3[r] - x0[r];
    }
    float F[3][3];
    #pragma unroll
    for (int r = 0; r < 3; ++r) {
        #pragma unroll
        for (int k = 0; k < 3; ++k)
            F[r][k] = d[r][0] * Rv[0 * 3 + k] + d[r][1] * Rv[1 * 3 + k] + d[r][2] * Rv[2 * 3 + k];
    }
    const float det = F[0][0] * (F[1][1] * F[2][2] - F[1][2] * F[2][1])
                    - F[0][1] * (F[1][0] * F[2][2] - F[1][2] * F[2][0])
                    + F[0][2] * (F[1][0] * F[2][1] - F[1][1] * F[2][0]);
    const float ld = logf(fmaxf(det, 1e-8f));
    float tr = 0.0f;
    #pragma unroll
    for (int r = 0; r < 3; ++r)
        #pragma unroll
        for (int k = 0; k < 3; ++k)
            tr += F[r][k] * F[r][k];
    const float psi = 0.5f * lam * ld * ld - mu * ld + 0.5f * mu * (tr - 3.0f);
    return sS * (psi * vol);
}

// Blocks [0, Vblocks): vertex terms, 1 vertex/thread.
// Blocks [Vblocks, ...): element terms, 2 elements/thread (stride blockDim).
__global__ void fused_kernel(const float* __restrict__ pn,
                             const float* __restrict__ pc,
                             const float* __restrict__ pp,
                             const float* __restrict__ mass,
                             const int*   __restrict__ elems,
                             const float* __restrict__ vols,
                             const float* __restrict__ rinv,
                             const float* __restrict__ lam_p,
                             const float* __restrict__ mu_p,
                             float* __restrict__ partials,
                             int V, int E, int Vblocks,
                             float sI, float sG, float sS) {
    float local = 0.0f;

    if ((int)blockIdx.x < Vblocks) {
        const int v = blockIdx.x * blockDim.x + threadIdx.x;
        if (v < V) {
            const float m  = __builtin_nontemporal_load(mass + v);
            const float p0 = __builtin_nontemporal_load(pc + 3 * v + 0);
            const float y  = __builtin_nontemporal_load(pc + 3 * v + 1);
            const float p2 = __builtin_nontemporal_load(pc + 3 * v + 2);
            // pn streaming read stays CACHED: it warms L2 for the gathers.
            const float n0 = pn[3 * v + 0];
            const float n1 = pn[3 * v + 1];
            const float n2 = pn[3 * v + 2];
            const float q0 = __builtin_nontemporal_load(pp + 3 * v + 0);
            const float q1 = __builtin_nontemporal_load(pp + 3 * v + 1);
            const float q2 = __builtin_nontemporal_load(pp + 3 * v + 2);
            const float a0 = n0 + q0 - 2.0f * p0;
            const float a1 = n1 + q1 - 2.0f * y;
            const float a2 = n2 + q2 - 2.0f * p2;
            local = sI * (m * (a0 * a0 + a1 * a1 + a2 * a2)) + sG * (m * y);
        }
    } else {
        const float lam = lam_p[0];
        const float mu  = mu_p[0];
        const int base = (blockIdx.x - Vblocks) * (2 * blockDim.x);
        const int e0 = base + threadIdx.x;
        const int e1 = e0 + blockDim.x;

        // Pull both index vectors + vols up front so the 8 gathers overlap.
        v4i idx0 = (v4i)(0), idx1 = (v4i)(0);
        float vol0 = 0.0f, vol1 = 0.0f;
        const bool ok0 = e0 < E, ok1 = e1 < E;
        if (ok0) { idx0 = __builtin_nontemporal_load(((const v4i*)elems) + e0);
                   vol0 = __builtin_nontemporal_load(vols + e0); }
        if (ok1) { idx1 = __builtin_nontemporal_load(((const v4i*)elems) + e1);
                   vol1 = __builtin_nontemporal_load(vols + e1); }
        if (ok0) local += elem_term(pn, idx0, vol0, rinv + 9 * (size_t)e0, lam, mu, sS);
        if (ok1) local += elem_term(pn, idx1, vol1, rinv + 9 * (size_t)e1, lam, mu, sS);
    }

    const float tot = blockReduceSum(local);
    if (threadIdx.x == 0) partials[blockIdx.x] = tot;
}

__global__ void reduce_kernel(const float* __restrict__ partials, int n,
                              float* __restrict__ out) {
    double s = 0.0;
    for (int i = threadIdx.x; i < n; i += blockDim.x)
        s += (double)partials[i];
    __shared__ double sm[256];
    sm[threadIdx.x] = s;
    __syncthreads();
    #pragma unroll
    for (int off = 128; off > 0; off >>= 1) {
        if (threadIdx.x < off) sm[threadIdx.x] += sm[threadIdx.x + off];
        __syncthreads();
    }
    if (threadIdx.x == 0) out[0] = (float)sm[0];
}

extern "C" void kernel_launch(void* const* d_in, const int* in_sizes, int n_in,
                              void* d_out, int out_size, void* d_ws, size_t ws_size,
                              hipStream_t stream) {
    const float* pos_next = (const float*)d_in[0];
    const float* pos_curr = (const float*)d_in[1];
    const float* pos_prev = (const float*)d_in[2];
    const float* mass     = (const float*)d_in[3];
    const int*   elements = (const int*)d_in[4];
    const float* rest_vol = (const float*)d_in[5];
    const float* rest_inv = (const float*)d_in[6];
    const float* lam_p    = (const float*)d_in[7];
    const float* mu_p     = (const float*)d_in[8];
    float* out = (float*)d_out;

    const int V = in_sizes[3];  // mass has V elements
    const int E = in_sizes[5];  // rest_volumes has E elements

    const float sI = 0.5f / (3.0f * (float)V);       // W_INERTIA * 0.5 / (3V)
    const float sG = -0.01f * GRAVITY_F / (float)V;  // W_GRAVITY * (-g) / V
    const float sS = 1.0f / (float)E;                // W_STRAIN / E

    const int block = 256;
    const int Vblocks = (V + block - 1) / block;
    const int Eblocks = (E + 2 * block - 1) / (2 * block);
    const int grid = Vblocks + Eblocks;

    float* partials = (float*)d_ws;  // grid floats; every slot overwritten

    fused_kernel<<<grid, block, 0, stream>>>(pos_next, pos_curr, pos_prev,
                                             mass, elements, rest_vol,
                                             rest_inv, lam_p, mu_p,
                                             partials, V, E, Vblocks,
                                             sI, sG, sS);
    reduce_kernel<<<1, 256, 0, stream>>>(partials, grid, out);
}

// Round 5
// 223.199 us; speedup vs baseline: 1.0623x; 1.0155x over previous
//
#include <hip/hip_runtime.h>

#define GRAVITY_F 9.81f

typedef int v4i __attribute__((ext_vector_type(4)));

__device__ __forceinline__ float blockReduceSum(float val) {
    #pragma unroll
    for (int off = 32; off > 0; off >>= 1)
        val += __shfl_down(val, off, 64);
    __shared__ float smem[16];
    const int lane = threadIdx.x & 63;
    const int wave = threadIdx.x >> 6;
    if (lane == 0) smem[wave] = val;
    __syncthreads();
    const int nwaves = (blockDim.x + 63) >> 6;
    val = 0.0f;
    if (wave == 0) {
        if (lane < nwaves) val = smem[lane];
        #pragma unroll
        for (int off = 8; off > 0; off >>= 1)
            val += __shfl_down(val, off, 64);
    }
    return val;  // valid on thread 0 only
}

#define EPT 4  // elements per thread

// Blocks [0, Eblocks): element terms, EPT elems/thread, load-first structure.
// Blocks [Eblocks, ...): vertex terms, 1 vertex/thread.
__global__ void __launch_bounds__(256, 4)
fused_kernel(const float* __restrict__ pn,
             const float* __restrict__ pc,
             const float* __restrict__ pp,
             const float* __restrict__ mass,
             const int*   __restrict__ elems,
             const float* __restrict__ vols,
             const float* __restrict__ rinv,
             const float* __restrict__ lam_p,
             const float* __restrict__ mu_p,
             float* __restrict__ partials,
             int V, int E, int Eblocks,
             float sI, float sG, float sS) {
    float local = 0.0f;

    if ((int)blockIdx.x < Eblocks) {
        const float lam = lam_p[0];
        const float mu  = mu_p[0];
        const int base = blockIdx.x * (EPT * 256) + threadIdx.x;

        // --- Phase A: element indices + vols (branch-free, clamped tail) ---
        int  ec[EPT];
        float sc[EPT];
        #pragma unroll
        for (int i = 0; i < EPT; ++i) {
            const int e = base + i * 256;
            ec[i] = e < E ? e : (E - 1);
            sc[i] = e < E ? sS : 0.0f;
        }
        v4i  idx[EPT];
        float vol[EPT];
        #pragma unroll
        for (int i = 0; i < EPT; ++i) {
            idx[i] = __builtin_nontemporal_load(((const v4i*)elems) + ec[i]);
            vol[i] = __builtin_nontemporal_load(vols + ec[i]);
        }

        // --- Phase B: all vertex gathers issued back-to-back ---
        float x[EPT][4][3];
        #pragma unroll
        for (int i = 0; i < EPT; ++i) {
            const float* v0 = pn + 3 * (size_t)idx[i].x;
            const float* v1 = pn + 3 * (size_t)idx[i].y;
            const float* v2 = pn + 3 * (size_t)idx[i].z;
            const float* v3 = pn + 3 * (size_t)idx[i].w;
            #pragma unroll
            for (int r = 0; r < 3; ++r) {
                x[i][0][r] = v0[r];
                x[i][1][r] = v1[r];
                x[i][2][r] = v2[r];
                x[i][3][r] = v3[r];
            }
        }

        // --- Phase C: rest_inv (streamed once — nontemporal) ---
        float R[EPT][9];
        #pragma unroll
        for (int i = 0; i < EPT; ++i) {
            const float* Rp = rinv + 9 * (size_t)ec[i];
            #pragma unroll
            for (int k = 0; k < 9; ++k)
                R[i][k] = __builtin_nontemporal_load(Rp + k);
        }

        // --- Phase D: compute ---
        #pragma unroll
        for (int i = 0; i < EPT; ++i) {
            float d[3][3];
            #pragma unroll
            for (int r = 0; r < 3; ++r) {
                d[r][0] = x[i][1][r] - x[i][0][r];
                d[r][1] = x[i][2][r] - x[i][0][r];
                d[r][2] = x[i][3][r] - x[i][0][r];
            }
            float F[3][3];
            #pragma unroll
            for (int r = 0; r < 3; ++r)
                #pragma unroll
                for (int k = 0; k < 3; ++k)
                    F[r][k] = d[r][0] * R[i][0 * 3 + k]
                            + d[r][1] * R[i][1 * 3 + k]
                            + d[r][2] * R[i][2 * 3 + k];
            const float det = F[0][0] * (F[1][1] * F[2][2] - F[1][2] * F[2][1])
                            - F[0][1] * (F[1][0] * F[2][2] - F[1][2] * F[2][0])
                            + F[0][2] * (F[1][0] * F[2][1] - F[1][1] * F[2][0]);
            const float ld = logf(fmaxf(det, 1e-8f));
            float tr = 0.0f;
            #pragma unroll
            for (int r = 0; r < 3; ++r)
                #pragma unroll
                for (int k = 0; k < 3; ++k)
                    tr += F[r][k] * F[r][k];
            const float psi = 0.5f * lam * ld * ld - mu * ld + 0.5f * mu * (tr - 3.0f);
            local += sc[i] * (psi * vol[i]);
        }
    } else {
        const int v = (blockIdx.x - Eblocks) * blockDim.x + threadIdx.x;
        if (v < V) {
            const float m  = __builtin_nontemporal_load(mass + v);
            const float p0 = __builtin_nontemporal_load(pc + 3 * v + 0);
            const float y  = __builtin_nontemporal_load(pc + 3 * v + 1);
            const float p2 = __builtin_nontemporal_load(pc + 3 * v + 2);
            // pn streaming read stays CACHED: it warms L2 for the gathers.
            const float n0 = pn[3 * v + 0];
            const float n1 = pn[3 * v + 1];
            const float n2 = pn[3 * v + 2];
            const float q0 = __builtin_nontemporal_load(pp + 3 * v + 0);
            const float q1 = __builtin_nontemporal_load(pp + 3 * v + 1);
            const float q2 = __builtin_nontemporal_load(pp + 3 * v + 2);
            const float a0 = n0 + q0 - 2.0f * p0;
            const float a1 = n1 + q1 - 2.0f * y;
            const float a2 = n2 + q2 - 2.0f * p2;
            local = sI * (m * (a0 * a0 + a1 * a1 + a2 * a2)) + sG * (m * y);
        }
    }

    const float tot = blockReduceSum(local);
    if (threadIdx.x == 0) partials[blockIdx.x] = tot;
}

__global__ void reduce_kernel(const float* __restrict__ partials, int n,
                              float* __restrict__ out) {
    double s = 0.0;
    for (int i = threadIdx.x; i < n; i += blockDim.x)
        s += (double)partials[i];
    __shared__ double sm[256];
    sm[threadIdx.x] = s;
    __syncthreads();
    #pragma unroll
    for (int off = 128; off > 0; off >>= 1) {
        if (threadIdx.x < off) sm[threadIdx.x] += sm[threadIdx.x + off];
        __syncthreads();
    }
    if (threadIdx.x == 0) out[0] = (float)sm[0];
}

extern "C" void kernel_launch(void* const* d_in, const int* in_sizes, int n_in,
                              void* d_out, int out_size, void* d_ws, size_t ws_size,
                              hipStream_t stream) {
    const float* pos_next = (const float*)d_in[0];
    const float* pos_curr = (const float*)d_in[1];
    const float* pos_prev = (const float*)d_in[2];
    const float* mass     = (const float*)d_in[3];
    const int*   elements = (const int*)d_in[4];
    const float* rest_vol = (const float*)d_in[5];
    const float* rest_inv = (const float*)d_in[6];
    const float* lam_p    = (const float*)d_in[7];
    const float* mu_p     = (const float*)d_in[8];
    float* out = (float*)d_out;

    const int V = in_sizes[3];  // mass has V elements
    const int E = in_sizes[5];  // rest_volumes has E elements

    const float sI = 0.5f / (3.0f * (float)V);       // W_INERTIA * 0.5 / (3V)
    const float sG = -0.01f * GRAVITY_F / (float)V;  // W_GRAVITY * (-g) / V
    const float sS = 1.0f / (float)E;                // W_STRAIN / E

    const int block = 256;
    const int Eblocks = (E + EPT * block - 1) / (EPT * block);
    const int Vblocks = (V + block - 1) / block;
    const int grid = Eblocks + Vblocks;

    float* partials = (float*)d_ws;  // grid floats; every slot overwritten

    fused_kernel<<<grid, block, 0, stream>>>(pos_next, pos_curr, pos_prev,
                                             mass, elements, rest_vol,
                                             rest_inv, lam_p, mu_p,
                                             partials, V, E, Eblocks,
                                             sI, sG, sS);
    reduce_kernel<<<1, 256, 0, stream>>>(partials, grid, out);
}

// Round 6
// 206.965 us; speedup vs baseline: 1.1456x; 1.0784x over previous
//
#include <hip/hip_runtime.h>
#include <hip/hip_fp16.h>

#define GRAVITY_F 9.81f
#define EPT 4  // elements per thread

typedef int v4i __attribute__((ext_vector_type(4)));

union PackedPos { uint2 u; __half h[4]; };

__device__ __forceinline__ float blockReduceSum(float val) {
    #pragma unroll
    for (int off = 32; off > 0; off >>= 1)
        val += __shfl_down(val, off, 64);
    __shared__ float smem[16];
    const int lane = threadIdx.x & 63;
    const int wave = threadIdx.x >> 6;
    if (lane == 0) smem[wave] = val;
    __syncthreads();
    const int nwaves = (blockDim.x + 63) >> 6;
    val = 0.0f;
    if (wave == 0) {
        if (lane < nwaves) val = smem[lane];
        #pragma unroll
        for (int off = 8; off > 0; off >>= 1)
            val += __shfl_down(val, off, 64);
    }
    return val;  // valid on thread 0 only
}

// Pack pos_next (fp32 x,y,z) -> half4 (8 B) so the gather target fits in a
// 4 MiB per-XCD L2. Cached (non-nt) write: we WANT it resident.
__global__ void pack_kernel(const float* __restrict__ pn,
                            uint2* __restrict__ out, int V) {
    const int v = blockIdx.x * blockDim.x + threadIdx.x;
    if (v >= V) return;
    PackedPos p;
    p.h[0] = __float2half(__builtin_nontemporal_load(pn + 3 * v + 0));
    p.h[1] = __float2half(__builtin_nontemporal_load(pn + 3 * v + 1));
    p.h[2] = __float2half(__builtin_nontemporal_load(pn + 3 * v + 2));
    p.h[3] = __half(0.0f);
    out[v] = p.u;
}

// Blocks [0, Eblocks): element terms, EPT elems/thread.
// Blocks [Eblocks, ...): vertex terms, 1 vertex/thread (exact fp32).
template <bool PACKED>
__global__ void __launch_bounds__(256, 4)
fused_kernel(const float* __restrict__ pn,
             const float* __restrict__ pc,
             const float* __restrict__ pp,
             const float* __restrict__ mass,
             const int*   __restrict__ elems,
             const float* __restrict__ vols,
             const float* __restrict__ rinv,
             const float* __restrict__ lam_p,
             const float* __restrict__ mu_p,
             const uint2* __restrict__ packed4,
             float* __restrict__ partials,
             int V, int E, int Eblocks,
             float sI, float sG, float sS) {
    float local = 0.0f;

    if ((int)blockIdx.x < Eblocks) {
        const float lam = lam_p[0];
        const float mu  = mu_p[0];
        const int base = blockIdx.x * (EPT * 256) + threadIdx.x;

        int  ec[EPT];
        float sc[EPT];
        #pragma unroll
        for (int i = 0; i < EPT; ++i) {
            const int e = base + i * 256;
            ec[i] = e < E ? e : (E - 1);
            sc[i] = e < E ? sS : 0.0f;
        }
        v4i  idx[EPT];
        float vol[EPT];
        #pragma unroll
        for (int i = 0; i < EPT; ++i) {
            idx[i] = __builtin_nontemporal_load(((const v4i*)elems) + ec[i]);
            vol[i] = __builtin_nontemporal_load(vols + ec[i]);
        }

        // Vertex gathers
        float x[EPT][4][3];
        if (PACKED) {
            uint2 g[EPT][4];
            #pragma unroll
            for (int i = 0; i < EPT; ++i) {
                g[i][0] = packed4[idx[i].x];
                g[i][1] = packed4[idx[i].y];
                g[i][2] = packed4[idx[i].z];
                g[i][3] = packed4[idx[i].w];
            }
            #pragma unroll
            for (int i = 0; i < EPT; ++i)
                #pragma unroll
                for (int j = 0; j < 4; ++j) {
                    PackedPos p; p.u = g[i][j];
                    x[i][j][0] = __half2float(p.h[0]);
                    x[i][j][1] = __half2float(p.h[1]);
                    x[i][j][2] = __half2float(p.h[2]);
                }
        } else {
            #pragma unroll
            for (int i = 0; i < EPT; ++i) {
                const float* v0 = pn + 3 * (size_t)idx[i].x;
                const float* v1 = pn + 3 * (size_t)idx[i].y;
                const float* v2 = pn + 3 * (size_t)idx[i].z;
                const float* v3 = pn + 3 * (size_t)idx[i].w;
                #pragma unroll
                for (int r = 0; r < 3; ++r) {
                    x[i][0][r] = v0[r];
                    x[i][1][r] = v1[r];
                    x[i][2][r] = v2[r];
                    x[i][3][r] = v3[r];
                }
            }
        }

        float R[EPT][9];
        #pragma unroll
        for (int i = 0; i < EPT; ++i) {
            const float* Rp = rinv + 9 * (size_t)ec[i];
            #pragma unroll
            for (int k = 0; k < 9; ++k)
                R[i][k] = __builtin_nontemporal_load(Rp + k);
        }

        #pragma unroll
        for (int i = 0; i < EPT; ++i) {
            float d[3][3];
            #pragma unroll
            for (int r = 0; r < 3; ++r) {
                d[r][0] = x[i][1][r] - x[i][0][r];
                d[r][1] = x[i][2][r] - x[i][0][r];
                d[r][2] = x[i][3][r] - x[i][0][r];
            }
            float F[3][3];
            #pragma unroll
            for (int r = 0; r < 3; ++r)
                #pragma unroll
                for (int k = 0; k < 3; ++k)
                    F[r][k] = d[r][0] * R[i][0 * 3 + k]
                            + d[r][1] * R[i][1 * 3 + k]
                            + d[r][2] * R[i][2 * 3 + k];
            const float det = F[0][0] * (F[1][1] * F[2][2] - F[1][2] * F[2][1])
                            - F[0][1] * (F[1][0] * F[2][2] - F[1][2] * F[2][0])
                            + F[0][2] * (F[1][0] * F[2][1] - F[1][1] * F[2][0]);
            const float ld = logf(fmaxf(det, 1e-8f));
            float tr = 0.0f;
            #pragma unroll
            for (int r = 0; r < 3; ++r)
                #pragma unroll
                for (int k = 0; k < 3; ++k)
                    tr += F[r][k] * F[r][k];
            const float psi = 0.5f * lam * ld * ld - mu * ld + 0.5f * mu * (tr - 3.0f);
            local += sc[i] * (psi * vol[i]);
        }
    } else {
        const int v = (blockIdx.x - Eblocks) * blockDim.x + threadIdx.x;
        if (v < V) {
            const float m  = __builtin_nontemporal_load(mass + v);
            const float p0 = __builtin_nontemporal_load(pc + 3 * v + 0);
            const float y  = __builtin_nontemporal_load(pc + 3 * v + 1);
            const float p2 = __builtin_nontemporal_load(pc + 3 * v + 2);
            const float n0 = __builtin_nontemporal_load(pn + 3 * v + 0);
            const float n1 = __builtin_nontemporal_load(pn + 3 * v + 1);
            const float n2 = __builtin_nontemporal_load(pn + 3 * v + 2);
            const float q0 = __builtin_nontemporal_load(pp + 3 * v + 0);
            const float q1 = __builtin_nontemporal_load(pp + 3 * v + 1);
            const float q2 = __builtin_nontemporal_load(pp + 3 * v + 2);
            const float a0 = n0 + q0 - 2.0f * p0;
            const float a1 = n1 + q1 - 2.0f * y;
            const float a2 = n2 + q2 - 2.0f * p2;
            local = sI * (m * (a0 * a0 + a1 * a1 + a2 * a2)) + sG * (m * y);
        }
    }

    const float tot = blockReduceSum(local);
    if (threadIdx.x == 0) partials[blockIdx.x] = tot;
}

__global__ void reduce_kernel(const float* __restrict__ partials, int n,
                              float* __restrict__ out) {
    double s = 0.0;
    for (int i = threadIdx.x; i < n; i += blockDim.x)
        s += (double)partials[i];
    __shared__ double sm[256];
    sm[threadIdx.x] = s;
    __syncthreads();
    #pragma unroll
    for (int off = 128; off > 0; off >>= 1) {
        if (threadIdx.x < off) sm[threadIdx.x] += sm[threadIdx.x + off];
        __syncthreads();
    }
    if (threadIdx.x == 0) out[0] = (float)sm[0];
}

extern "C" void kernel_launch(void* const* d_in, const int* in_sizes, int n_in,
                              void* d_out, int out_size, void* d_ws, size_t ws_size,
                              hipStream_t stream) {
    const float* pos_next = (const float*)d_in[0];
    const float* pos_curr = (const float*)d_in[1];
    const float* pos_prev = (const float*)d_in[2];
    const float* mass     = (const float*)d_in[3];
    const int*   elements = (const int*)d_in[4];
    const float* rest_vol = (const float*)d_in[5];
    const float* rest_inv = (const float*)d_in[6];
    const float* lam_p    = (const float*)d_in[7];
    const float* mu_p     = (const float*)d_in[8];
    float* out = (float*)d_out;

    const int V = in_sizes[3];  // mass has V elements
    const int E = in_sizes[5];  // rest_volumes has E elements

    const float sI = 0.5f / (3.0f * (float)V);       // W_INERTIA * 0.5 / (3V)
    const float sG = -0.01f * GRAVITY_F / (float)V;  // W_GRAVITY * (-g) / V
    const float sS = 1.0f / (float)E;                // W_STRAIN / E

    const int block = 256;
    const int Eblocks = (E + EPT * block - 1) / (EPT * block);
    const int Vblocks = (V + block - 1) / block;
    const int grid = Eblocks + Vblocks;

    float* partials = (float*)d_ws;  // grid floats; every slot overwritten
    const size_t part_bytes = ((size_t)grid * sizeof(float) + 255) & ~(size_t)255;
    const size_t need = part_bytes + (size_t)V * 8;

    if (ws_size >= need) {
        uint2* packed4 = (uint2*)((char*)d_ws + part_bytes);
        pack_kernel<<<(V + block - 1) / block, block, 0, stream>>>(pos_next, packed4, V);
        fused_kernel<true><<<grid, block, 0, stream>>>(pos_next, pos_curr, pos_prev,
                                                       mass, elements, rest_vol,
                                                       rest_inv, lam_p, mu_p,
                                                       packed4, partials,
                                                       V, E, Eblocks, sI, sG, sS);
    } else {
        fused_kernel<false><<<grid, block, 0, stream>>>(pos_next, pos_curr, pos_prev,
                                                        mass, elements, rest_vol,
                                                        rest_inv, lam_p, mu_p,
                                                        nullptr, partials,
                                                        V, E, Eblocks, sI, sG, sS);
    }
    reduce_kernel<<<1, 256, 0, stream>>>(partials, grid, out);
}